// Round 2
// 624.244 us; speedup vs baseline: 1.2000x; 1.2000x over previous
//
#include <hip/hip_runtime.h>

typedef __attribute__((ext_vector_type(8))) short bf16x8;
typedef __attribute__((ext_vector_type(4))) float f32x4;

// Problem constants
#define B_   16
#define C_   64
#define H_   64
#define W_   64
#define HD_  128
#define K_   320      // C + 2*HD
#define SW_  127      // H+W-1

// Decomposition: 4 hd-groups (32 hd each) x 64 col-clusters (16 cols each) = 256 blocks
#define NG    4
#define GH    32      // hd per group
#define NCG   64      // clusters
#define TC    16      // cols per cluster
#define NT    640     // threads per block (10 waves)
#define ROWS  160     // gate rows per block (5 gates x 32 hd)
#define NKT   10      // K/32 k-tiles
#define NRT   10      // ROWS/16 row-tiles (== waves)
#define SSTR  19      // Ss row stride
#define GPS   17      // gate-panel stride

// Workspace layout (float offsets).
// h exchange is a DEPTH-4 ring (slot = j&3): gives the right-neighbor WAR check
// 3 steps of slack so it never blocks in steady state (was tight lockstep).
#define HBSLOT 131072LL
#define HB(s)  ((long long)(s) * HBSLOT)   // 4 slots: [0, 524288)
#define CBX    524288LL                    // c boundary ring: 4 x NCG x NG x GH = 32768
#define CNT    557056LL                    // 64 counters, stride 32 ints
#define GCNT   559104LL                    // 64 WAR tokens, stride 32 ints
#define AFB    561152LL                    // A-fragments: 204800 floats (hi+lo bf16)
#define AF_N   204800LL
#define XT     765952LL                    // xT[b][hr][w][c]
#define XT_N   4194304LL
#define WS_MIN (AFB + AF_N)
#define WS_XT  (XT + XT_N)

__device__ __forceinline__ float sigm(float v) { return 1.f / (1.f + __expf(-v)); }
__device__ __forceinline__ float tanh_fast(float v) {
    float e = __expf(2.f * v);
    return 1.f - 2.f / (e + 1.f);
}

// Flags: relaxed agent-scope atomics (coherence point).
__device__ __forceinline__ int rload(int* p) {
    return __hip_atomic_load(p, __ATOMIC_RELAXED, __HIP_MEMORY_SCOPE_AGENT);
}
__device__ __forceinline__ void rbump(int* p) {
    __hip_atomic_fetch_add(p, 1, __ATOMIC_RELAXED, __HIP_MEMORY_SCOPE_AGENT);
}
__device__ __forceinline__ void wait_ge(int* p, int tgt) {
    while (rload(p) < tgt) { }       // busy poll: lowest discovery latency
    __atomic_signal_fence(__ATOMIC_ACQUIRE);
}

// Coherence-point (sc0 sc1) data ops: bypass L1/L2; rest of L2 (A-frags, xT) stays warm.
__device__ __forceinline__ f32x4 ld4_sc(const float* p) {
    f32x4 v;
    asm volatile("global_load_dwordx4 %0, %1, off sc0 sc1\n\ts_waitcnt vmcnt(0)"
                 : "=v"(v) : "v"(p) : "memory");
    return v;
}
__device__ __forceinline__ void st1_nw(float* p, float v) {   // no-wait store
    asm volatile("global_store_dword %0, %1, off sc0 sc1" :: "v"(p), "v"(v) : "memory");
}
__device__ __forceinline__ void vm0() {
    asm volatile("s_waitcnt vmcnt(0)" ::: "memory");
}

__device__ __forceinline__ uint bf16hi(uint u) { return (u + 0x7FFFu + ((u >> 16) & 1u)) >> 16; }

// ---------------------------------------------------------------------------
// Prep: zero counters; build A-fragments (split-bf16, MFMA lane order).
// h/c rings need no zeroing: persist uses j>0 guards (step 0 state == 0).
// ---------------------------------------------------------------------------
__global__ void lstm_prep(const float* __restrict__ w_is,
                          const float* __restrict__ w_ss,
                          float* __restrict__ ws, long long n_ws)
{
    const long long stride = (long long)gridDim.x * blockDim.x;
    const long long t0 = (long long)blockIdx.x * blockDim.x + threadIdx.x;

    long long ze = CNT + 4096; if (ze > n_ws) ze = n_ws;
    for (long long i = CNT + t0; i < ze; i += stride) ws[i] = 0.f;

    if (n_ws >= WS_MIN) {
        ushort* af = (ushort*)(ws + AFB);
        for (long long e = t0; e < AF_N; e += stride) {
            int idx   = (int)e;
            int chunk = idx >> 9;           // (g*NRT+rt)*NKT + kt
            int lane  = (idx >> 3) & 63;
            int jj    = idx & 7;
            int g  = chunk / (NRT * NKT);
            int rm = chunk % (NRT * NKT);
            int rt = rm / NKT, kt = rm % NKT;
            int m = lane & 15, quad = lane >> 4;
            int r = rt * 16 + m;
            int q = r >> 5, hl = r & 31;
            int o = q * HD_ + g * GH + hl;
            int k = kt * 32 + quad * 8 + jj;
            float v;
            if (k < C_)            v = w_is[o * C_ + k];
            else if (k < C_ + HD_) v = w_ss[(o * HD_ + (k - C_)) * 2 + 1];
            else                   v = w_ss[(o * HD_ + (k - C_ - HD_)) * 2 + 0];
            uint uh = bf16hi(__float_as_uint(v));
            float rl = v - __uint_as_float(uh << 16);
            uint ul = bf16hi(__float_as_uint(rl));
            int base = chunk * 1024 + lane * 16 + jj;   // ushort units
            af[base]     = (ushort)uh;
            af[base + 8] = (ushort)ul;
        }
    }
}

// ---------------------------------------------------------------------------
// Coalesced transpose: x[b][c][hr][w] -> xT[b][hr][w][c] via 64x64 LDS tile.
// Both global sides coalesced (was a stride-16KB scalar gather, ~16x overfetch).
// ---------------------------------------------------------------------------
__global__ void lstm_xpose(const float* __restrict__ x, float* __restrict__ ws)
{
    __shared__ float L[64 * 65];
    const int b = blockIdx.x >> 6, hr = blockIdx.x & 63;
    const int tid = threadIdx.x;          // 256 threads
    #pragma unroll
    for (int it = 0; it < 16; ++it) {
        int c = it * 4 + (tid >> 6), w = tid & 63;
        L[c * 65 + w] = x[(((size_t)b * C_ + c) * H_ + hr) * W_ + w];
    }
    __syncthreads();
    float* xt = ws + XT;
    #pragma unroll
    for (int it = 0; it < 16; ++it) {
        int w = it * 4 + (tid >> 6), c = tid & 63;
        xt[(((size_t)b * H_ + hr) * W_ + w) * C_ + c] = L[c * 65 + w];
    }
}

// ---------------------------------------------------------------------------
// Persistent kernel: 127 diagonal steps.
// Latency chain per step minimized: 3 dependency polls run in PARALLEL waves;
// depth-4 rings relax WAR to 3-step slack; A hi AND lo pinned in VGPRs
// (no L2 stream in GEMM); FULL 4-term split-bf16 (3-term failed absmax by 1.5%);
// producer tail = one drain+sync then bump (Cs/out/prefetch after the bump).
// ---------------------------------------------------------------------------
__global__ void __launch_bounds__(NT, 3) lstm_persist(
    const float* __restrict__ x,
    const float* __restrict__ ws_c,
    const float* __restrict__ b_is,
    const float* __restrict__ b_ss,
    float* __restrict__ out,
    float* __restrict__ ws,
    int use_xt)
{
    __shared__ float Ss[192 * SSTR];    // rows 0..63: x [k][col+1]; 64..191: h [i][colp]
    __shared__ float Gp[ROWS * GPS];    // gate panel (un-aliased from Ss)
    __shared__ uint  Bf[NKT * 576];     // B-fragments: per kt, 64 lanes x (16B hi + 16B lo)
    __shared__ float Cs[17 * GH];       // persistent c panel [colp][hl], colp 0 = left boundary
    __shared__ float bias_s[ROWS];

    const int tid = threadIdx.x;
    const int cgp = blockIdx.x >> 2;
    const int g   = blockIdx.x & 3;
    const int n0  = cgp * TC;
    const int inb  = (n0 & 63) != 0;
    const int hasr = ((n0 + TC) & 63) != 0;

    int* cntp  = (int*)(ws + CNT);
    int* gcntp = (int*)(ws + GCNT);
    float* cbx = ws + CBX;
    const float* xt = ws_c + XT;
    const uint4* afq = (const uint4*)(ws_c + AFB);

    if (tid < ROWS) {
        int q = tid >> 5, hl = tid & 31;
        int o = q * HD_ + g * GH + hl;
        bias_s[tid] = b_is[o] + b_ss[o];
    }
    if (tid < 17 * GH) Cs[tid] = 0.f;   // c(0) = 0

    const int lane = tid & 63;
    const int wv   = tid >> 6;          // wave = row-tile rt in [0,10)
    const int quad = lane >> 4;
    const int colc = lane & 15;
    uint* bfp = &Bf[lane * 8 + ((lane >> 2) << 2)];
    const uint4* ap0 = afq + (size_t)((g * NRT + wv) * NKT) * 128 + lane * 2;

    // ---- A hi AND lo fragments pinned in registers (asm anchor = sole def) ----
    bf16x8 Ahr[NKT], Alr[NKT];
    #pragma unroll
    for (int kt = 0; kt < NKT; ++kt) {
        uint4 ha = ap0[kt * 128];
        Ahr[kt] = *(bf16x8*)&ha;
        asm volatile("" : "+v"(Ahr[kt]));
        uint4 la = ap0[kt * 128 + 1];
        Alr[kt] = *(bf16x8*)&la;
        asm volatile("" : "+v"(Alr[kt]));
    }

    float xr[2];
#define PREFETCH(JJ)                                                          \
    _Pragma("unroll")                                                         \
    for (int t = 0; t < 2; ++t) {                                             \
        int idx = tid + t * NT;                                               \
        xr[t] = 0.f;                                                          \
        if (idx < C_ * TC) {                                                  \
            int c = idx & 63, col = idx >> 6;                                 \
            int n = n0 + col, b = n >> 6, hr = n & 63;                        \
            int w = (JJ) - hr;                                                \
            if ((unsigned)w < (unsigned)W_)                                   \
                xr[t] = use_xt ? xt[(((size_t)b * H_ + hr) * W_ + w) * C_ + c]\
                               : x [(((size_t)b * C_ + c) * H_ + hr) * W_ + w];\
        }                                                                     \
    }

    PREFETCH(0)

    for (int j = 0; j < SW_; ++j) {
        const float* hc = ws + HB((j + 3) & 3);   // read slot j-1
        float*       hn = ws + HB(j & 3);         // write slot j

        // ---- P0: x panel write + PARALLEL dependency polls (3 distinct waves) ----
        #pragma unroll
        for (int t = 0; t < 2; ++t) {
            int idx = tid + t * NT;
            if (idx < C_ * TC) {
                int c = idx & 63, col = idx >> 6;
                Ss[c * SSTR + col + 1] = xr[t];
            }
        }
        if (tid == NT - 1) {                 // wave 9: own-cluster RAW
            if (j > 0) wait_ge(cntp + cgp * 32, 4 * j);
        } else if (tid == NT - 65) {         // wave 8: left-neighbor RAW
            if (j > 0 && inb) wait_ge(cntp + (cgp - 1) * 32, 4 * j);
        } else if (tid == NT - 129) {        // wave 7: right-neighbor WAR, 3-step slack
            if (j >= 4 && hasr) wait_ge(gcntp + (cgp + 1) * 32, 4 * (j - 2));
        }
        __syncthreads();

        // ---- P1: h gather (sc float4) + c boundary from rings ----
        if (tid < 544) {                                 // 17 cols x 32 float4
            int colp = tid >> 5, i4 = tid & 31;
            int n = n0 - 1 + colp;
            f32x4 v = {0.f, 0.f, 0.f, 0.f};
            if (j > 0 && (colp > 0 || inb)) v = ld4_sc(hc + (size_t)n * HD_ + i4 * 4);
            #pragma unroll
            for (int r = 0; r < 4; ++r)
                Ss[(64 + i4 * 4 + r) * SSTR + colp] = v[r];
        } else if (tid >= 576 && tid < 584) {            // c boundary column (8 x float4)
            int q4 = tid - 576;
            f32x4 v = {0.f, 0.f, 0.f, 0.f};
            if (inb && j > 0)
                v = ld4_sc(cbx + (((size_t)((j - 1) & 3) * NCG + (cgp - 1)) * NG + g) * GH + q4 * 4);
            #pragma unroll
            for (int r = 0; r < 4; ++r) Cs[q4 * 4 + r] = v[r];
        }
        __syncthreads();
        if (tid == 0) rbump(gcntp + cgp * 32);           // step-(j-1) state fully read

        // ---- P2: convert S panel to split-bf16 B-fragments (kt = wv) ----
        {
            int kb = wv * 32 + quad * 8;
            uint hv[4], lv[4];
            #pragma unroll
            for (int p = 0; p < 4; ++p) {
                int k0 = kb + 2 * p;
                float v0 = (k0 < 192) ? Ss[k0 * SSTR + colc + 1] : Ss[(k0 - 128) * SSTR + colc];
                int k1 = k0 + 1;
                float v1 = (k1 < 192) ? Ss[k1 * SSTR + colc + 1] : Ss[(k1 - 128) * SSTR + colc];
                uint h0 = bf16hi(__float_as_uint(v0));
                uint h1 = bf16hi(__float_as_uint(v1));
                float r0 = v0 - __uint_as_float(h0 << 16);
                float r1 = v1 - __uint_as_float(h1 << 16);
                uint l0 = bf16hi(__float_as_uint(r0));
                uint l1 = bf16hi(__float_as_uint(r1));
                hv[p] = h0 | (h1 << 16);
                lv[p] = l0 | (l1 << 16);
            }
            uint* bp = bfp + wv * 576;
            *(uint4*)bp       = make_uint4(hv[0], hv[1], hv[2], hv[3]);
            *(uint4*)(bp + 4) = make_uint4(lv[0], lv[1], lv[2], lv[3]);
        }
        __syncthreads();

        // ---- P3: GEMM, K=320, FULL 4-term split-bf16 ----
        f32x4 acc = {0.f, 0.f, 0.f, 0.f};
        #pragma unroll
        for (int kt = 0; kt < NKT; ++kt) {
            const uint* bp = bfp + kt * 576;
            uint4 hb = *(const uint4*)bp;
            uint4 lb = *(const uint4*)(bp + 4);
            bf16x8 Bh = *(bf16x8*)&hb, Bl = *(bf16x8*)&lb;
            acc = __builtin_amdgcn_mfma_f32_16x16x32_bf16(Ahr[kt], Bh, acc, 0, 0, 0);
            acc = __builtin_amdgcn_mfma_f32_16x16x32_bf16(Ahr[kt], Bl, acc, 0, 0, 0);
            acc = __builtin_amdgcn_mfma_f32_16x16x32_bf16(Alr[kt], Bh, acc, 0, 0, 0);
            acc = __builtin_amdgcn_mfma_f32_16x16x32_bf16(Alr[kt], Bl, acc, 0, 0, 0);
        }

        // ---- gates to LDS (C/D layout: row = quad*4+reg, col = lane&15) ----
        #pragma unroll
        for (int r = 0; r < 4; ++r)
            Gp[(wv * 16 + quad * 4 + r) * GPS + colc] = acc[r];
        __syncthreads();

        // ---- P4: nonlinearity; issue h + c-boundary stores; single drain ----
        float hv_keep = 0.f, cv_keep = 0.f;
        size_t out_idx = 0;
        int do_out = 0;
        const int active = (tid < GH * TC);
        const int hl = tid & 31, col = tid >> 5;
        if (active) {
            int n = n0 + col, b = n >> 6, hr = n & 63;
            int hd = g * GH + hl;
            float go  = Gp[(0 * GH + hl) * GPS + col] + bias_s[0 * GH + hl];
            float gfl = Gp[(1 * GH + hl) * GPS + col] + bias_s[1 * GH + hl];
            float gfu = Gp[(2 * GH + hl) * GPS + col] + bias_s[2 * GH + hl];
            float gi  = Gp[(3 * GH + hl) * GPS + col] + bias_s[3 * GH + hl];
            float gg  = Gp[(4 * GH + hl) * GPS + col] + bias_s[4 * GH + hl];
            float so = sigm(go), sfl = sigm(gfl), sfu = sigm(gfu), si = sigm(gi);
            float tg = tanh_fast(gg);
            float cp = Cs[(col + 1) * GH + hl];
            float cs = Cs[col * GH + hl];
            float cv = sfl * cp + sfu * cs + si * tg;
            float hv = so * tanh_fast(cv);
            cv_keep = cv; hv_keep = hv;
            if (col == TC - 1)
                st1_nw(cbx + (((size_t)(j & 3) * NCG + cgp) * NG + g) * GH + hl, cv);
            st1_nw(hn + (size_t)n * HD_ + g * GH + hl, hv);
            int w = j - hr;
            if ((unsigned)w < (unsigned)W_) {
                do_out = 1;
                out_idx = (((size_t)b * HD_ + hd) * H_ + hr) * W_ + w;
            }
        }
        vm0();                                            // all sc stores acked
        __syncthreads();

        // ---- P5: signal, then local epilogue off the exchange path ----
        if (tid == 0) rbump(cntp + cgp * 32);             // step j finished
        if (active) Cs[(col + 1) * GH + hl] = cv_keep;    // Cs reads done pre-sync
        if (do_out) out[out_idx] = hv_keep;               // plain cached
        if (j + 1 < SW_) { PREFETCH(j + 1) }              // overlap next x load
    }
#undef PREFETCH
}

// ---------------------------------------------------------------------------
extern "C" void kernel_launch(void* const* d_in, const int* in_sizes, int n_in,
                              void* d_out, int out_size, void* d_ws, size_t ws_size,
                              hipStream_t stream)
{
    const float* x    = (const float*)d_in[0];
    const float* w_is = (const float*)d_in[1];
    const float* b_is = (const float*)d_in[2];
    const float* w_ss = (const float*)d_in[3];
    const float* b_ss = (const float*)d_in[4];
    float* out = (float*)d_out;
    float* ws  = (float*)d_ws;

    const long long n_ws = (long long)(ws_size / 4);
    const int use_xt = (n_ws >= WS_XT) ? 1 : 0;

    hipLaunchKernelGGL(lstm_prep, dim3(512), dim3(256), 0, stream,
                       w_is, w_ss, ws, n_ws);
    if (use_xt)
        hipLaunchKernelGGL(lstm_xpose, dim3(B_ * H_), dim3(256), 0, stream, x, ws);

    hipLaunchKernelGGL(lstm_persist, dim3(NG * NCG), dim3(NT), 0, stream,
                       x, ws, b_is, b_ss, out, ws, use_xt);
}

// Round 4
// 579.624 us; speedup vs baseline: 1.2924x; 1.0770x over previous
//
#include <hip/hip_runtime.h>

typedef __attribute__((ext_vector_type(8))) short bf16x8;
typedef __attribute__((ext_vector_type(4))) float f32x4;
typedef __attribute__((ext_vector_type(4))) uint  u32x4;

// Problem constants
#define B_   16
#define C_   64
#define H_   64
#define W_   64
#define HD_  128
#define K_   320      // C + 2*HD
#define SW_  127      // H+W-1

// Decomposition: 4 hd-groups (32 hd each) x 64 col-clusters (16 cols each) = 256 blocks
#define NG    4
#define GH    32      // hd per group
#define NCG   64      // clusters
#define TC    16      // cols per cluster
#define NT    640     // threads per block (10 waves)
#define ROWS  160     // gate rows per block (5 gates x 32 hd)
#define NKT   10      // K/32 k-tiles
#define GPS   17      // gate-panel stride

// Workspace layout (float/uint offsets).
// h ring: 4 slots x 1024 cols x 128 hd, fp32 with pass-parity tag in the
// mantissa LSB (error 2^-24 — numerically free, unlike round-3's lo-bf16 LSB
// which cost 1.2e-2 of absmax). Per-word tags: no tearing, data is its own
// flag, RAW chain = store -> poll-hit (1 MALL hop). Prep wipes rings to
// tag=1 (pass -1) so pass-0 polls can't accept residue; later passes are
// protected because the same block re-polled the slot one pass earlier.
#define HSLOT  131072LL
#define CBX    524288LL                    // c boundary ring: 4 x NCG x NG x GH
#define CNT    557056LL                    // (legacy region, zeroed)
#define GCNT   559104LL                    // 64 WAR tokens, stride 32 ints
#define AFB    561152LL                    // A-fragments: 204800 floats (hi+lo bf16)
#define AF_N   204800LL
#define XT     765952LL                    // xT[b][hr][w][c]
#define XT_N   4194304LL
#define WS_MIN (AFB + AF_N)
#define WS_XT  (XT + XT_N)

#define POLL_CAP (1 << 20)   // safety: a protocol bug fails absmax instead of hanging

__device__ __forceinline__ float sigm(float v) { return 1.f / (1.f + __expf(-v)); }
__device__ __forceinline__ float tanh_fast(float v) {
    float e = __expf(2.f * v);
    return 1.f - 2.f / (e + 1.f);
}

__device__ __forceinline__ int rload(int* p) {
    return __hip_atomic_load(p, __ATOMIC_RELAXED, __HIP_MEMORY_SCOPE_AGENT);
}
__device__ __forceinline__ void rbump(int* p) {
    __hip_atomic_fetch_add(p, 1, __ATOMIC_RELAXED, __HIP_MEMORY_SCOPE_AGENT);
}
__device__ __forceinline__ void wait_ge(int* p, int tgt) {
    int guard = 0;
    while (rload(p) < tgt) { if (++guard > POLL_CAP) break; }
    __atomic_signal_fence(__ATOMIC_ACQUIRE);
}

// Coherence-point (sc0 sc1) ops: bypass L1/L2; weights/xT stay L2-warm.
__device__ __forceinline__ void stu_nw(uint* p, uint v) {     // fire-and-forget
    asm volatile("global_store_dword %0, %1, off sc0 sc1" :: "v"(p), "v"(v) : "memory");
}

// Poll two 16B chunks until every 32-bit word's LSB == want (batched loads, one wait).
__device__ __forceinline__ void poll2(const uint* p0, const uint* p1, uint want,
                                      u32x4& A, u32x4& B) {
    int guard = 0;
    while (true) {
        u32x4 a, b;
        asm volatile("global_load_dwordx4 %0, %2, off sc0 sc1\n\t"
                     "global_load_dwordx4 %1, %3, off sc0 sc1\n\t"
                     "s_waitcnt vmcnt(0)"
                     : "=&v"(a), "=&v"(b) : "v"(p0), "v"(p1) : "memory");
        uint m = a[0] & a[1] & a[2] & a[3] & b[0] & b[1] & b[2] & b[3];
        uint o = a[0] | a[1] | a[2] | a[3] | b[0] | b[1] | b[2] | b[3];
        bool ok = want ? ((m & 1u) != 0u) : ((o & 1u) == 0u);
        if (ok || ++guard > POLL_CAP) { A = a; B = b; return; }
    }
}
__device__ __forceinline__ void poll1(const uint* p, uint want, u32x4& A) {
    int guard = 0;
    while (true) {
        u32x4 a;
        asm volatile("global_load_dwordx4 %0, %1, off sc0 sc1\n\ts_waitcnt vmcnt(0)"
                     : "=&v"(a) : "v"(p) : "memory");
        uint m = a[0] & a[1] & a[2] & a[3];
        uint o = a[0] | a[1] | a[2] | a[3];
        bool ok = want ? ((m & 1u) != 0u) : ((o & 1u) == 0u);
        if (ok || ++guard > POLL_CAP) { A = a; return; }
    }
}

__device__ __forceinline__ uint bf16hi(uint u) { return (u + 0x7FFFu + ((u >> 16) & 1u)) >> 16; }
__device__ __forceinline__ uint2 splitbf(float v) {
    uint uh = bf16hi(__float_as_uint(v));
    float rl = v - __uint_as_float(uh << 16);
    uint ul = bf16hi(__float_as_uint(rl));
    return make_uint2(uh, ul);
}

// ---------------------------------------------------------------------------
// Prep: wipe rings to tag=1 (0x00000001); zero counters; build A-fragments
// (split-bf16, MFMA lane order). sc stores so the wipe is at the coherence
// point before persist's sc polls.
// ---------------------------------------------------------------------------
__global__ void lstm_prep(const float* __restrict__ w_is,
                          const float* __restrict__ w_ss,
                          float* __restrict__ ws, long long n_ws)
{
    const long long stride = (long long)gridDim.x * blockDim.x;
    const long long t0 = (long long)blockIdx.x * blockDim.x + threadIdx.x;
    uint* wsu = (uint*)ws;

    for (long long i = t0; i < 524288LL + 32768LL; i += stride) {
        long long a = (i < 524288LL) ? i : (CBX + (i - 524288LL));
        stu_nw(wsu + a, 0x00000001u);
    }
    for (long long i = CNT + t0; i < CNT + 4096; i += stride)
        stu_nw(wsu + i, 0u);

    if (n_ws >= WS_MIN) {
        ushort* af = (ushort*)(ws + AFB);
        for (long long e = t0; e < AF_N; e += stride) {
            int idx   = (int)e;
            int chunk = idx >> 9;           // (g*NRT+rt)*NKT + kt
            int lane  = (idx >> 3) & 63;
            int jj    = idx & 7;
            int g  = chunk / (10 * NKT);
            int rm = chunk % (10 * NKT);
            int rt = rm / NKT, kt = rm % NKT;
            int m = lane & 15, quad = lane >> 4;
            int r = rt * 16 + m;
            int q = r >> 5, hl = r & 31;
            int o = q * HD_ + g * GH + hl;
            int k = kt * 32 + quad * 8 + jj;
            float v;
            if (k < C_)            v = w_is[o * C_ + k];
            else if (k < C_ + HD_) v = w_ss[(o * HD_ + (k - C_)) * 2 + 1];
            else                   v = w_ss[(o * HD_ + (k - C_ - HD_)) * 2 + 0];
            uint uh = bf16hi(__float_as_uint(v));
            float rl = v - __uint_as_float(uh << 16);
            uint ul = bf16hi(__float_as_uint(rl));
            int base = chunk * 1024 + lane * 16 + jj;   // ushort units
            af[base]     = (ushort)uh;
            af[base + 8] = (ushort)ul;
        }
    }
}

// ---------------------------------------------------------------------------
// Coalesced transpose: x[b][c][hr][w] -> xT[b][hr][w][c] via 64x64 LDS tile.
// ---------------------------------------------------------------------------
__global__ void lstm_xpose(const float* __restrict__ x, float* __restrict__ ws)
{
    __shared__ float L[64 * 65];
    const int b = blockIdx.x >> 6, hr = blockIdx.x & 63;
    const int tid = threadIdx.x;          // 256 threads
    #pragma unroll
    for (int it = 0; it < 16; ++it) {
        int c = it * 4 + (tid >> 6), w = tid & 63;
        L[c * 65 + w] = x[(((size_t)b * C_ + c) * H_ + hr) * W_ + w];
    }
    __syncthreads();
    float* xt = ws + XT;
    #pragma unroll
    for (int it = 0; it < 16; ++it) {
        int w = it * 4 + (tid >> 6), c = tid & 63;
        xt[(((size_t)b * H_ + hr) * W_ + w) * C_ + c] = L[c * 65 + w];
    }
}

// ---------------------------------------------------------------------------
// Persistent kernel: 127 diagonal steps, self-tagged dataflow.
// h is exchanged as fp32 with a pass-parity tag in the mantissa LSB:
// consumers poll the data itself (1 MALL hop) then split to bf16 hi/lo in
// registers — no counters on the RAW path, no vm0 drain, no LDS h-panel.
// 2 barriers/step; x-frag waves poll next step during producers' nonlin.
// ---------------------------------------------------------------------------
__global__ void __launch_bounds__(NT, 3) lstm_persist(
    const float* __restrict__ x,
    const float* __restrict__ ws_c,
    const float* __restrict__ b_is,
    const float* __restrict__ b_ss,
    float* __restrict__ out,
    float* __restrict__ ws,
    int use_xt)
{
    __shared__ uint  Bf[NKT * 576];     // B-fragments: per kt, 64 lanes x (16B hi + 16B lo)
    __shared__ float Gp[ROWS * GPS];    // gate panel
    __shared__ float Cs[2][17 * GH];    // double-buffered c panel [colp][hl]
    __shared__ float bias_s[ROWS];

    const int tid = threadIdx.x;
    const int cgp = blockIdx.x >> 2;
    const int g   = blockIdx.x & 3;
    const int n0  = cgp * TC;
    const int inb  = (n0 & 63) != 0;
    const int hasr = ((n0 + TC) & 63) != 0;

    uint* hring = (uint*)ws;
    uint* cring = (uint*)(ws + CBX);
    int*  gcntp = (int*)(ws + GCNT);
    const float* xt = ws_c + XT;
    const uint4* afq = (const uint4*)(ws_c + AFB);

    if (tid < ROWS) {
        int q = tid >> 5, hl = tid & 31;
        int o = q * HD_ + g * GH + hl;
        bias_s[tid] = b_is[o] + b_ss[o];
    }
    if (tid < 17 * GH) Cs[0][tid] = 0.f;    // step-0 c panel
    if (tid >= 544 && tid < 544 + GH) Cs[1][tid - 544] = 0.f;   // boundary col, buf 1

    const int lane = tid & 63;
    const int wv   = tid >> 6;          // wave = GEMM row-tile rt in [0,10)
    const int quad = lane >> 4;
    const int colc = lane & 15;
    uint* bfr = &Bf[lane * 8 + ((lane >> 2) << 2)];   // GEMM read base
    const uint4* ap0 = afq + (size_t)((g * 10 + wv) * NKT) * 128 + lane * 2;

    // ---- P1 role precompute ----
    const int wkt = (wv < 8) ? (wv + 2) : (wv - 8);   // Bf k-tile this thread builds
    uint* wp = bfr + wkt * 576;                        // Bf write base
    // h-threads (wv<8)
    int hn = 0, hd0 = 0, hskip = 0;
    if (wv < 8) {
        if (wv < 4) { hn = n0 + colc;     hd0 = wv * 32 + quad * 8; }
        else        { hn = n0 - 1 + colc; hd0 = (wv - 4) * 32 + quad * 8;
                      hskip = (colc == 0 && !inb); }
    }
    // x-threads (wv 8,9)
    const int xc0 = (wv >= 8) ? ((wv - 8) * 32 + quad * 8) : 0;
    const int xn = n0 + colc, xb = xn >> 6, xhr = xn & 63;
    const int ii = tid - 512;           // extra duties for wave 8

    // ---- A hi AND lo fragments pinned in registers ----
    bf16x8 Ahr[NKT], Alr[NKT];
    #pragma unroll
    for (int kt = 0; kt < NKT; ++kt) {
        uint4 ha = ap0[kt * 128];
        Ahr[kt] = *(bf16x8*)&ha;
        asm volatile("" : "+v"(Ahr[kt]));
        uint4 la = ap0[kt * 128 + 1];
        Alr[kt] = *(bf16x8*)&la;
        asm volatile("" : "+v"(Alr[kt]));
    }

    __syncthreads();

    for (int j = 0; j < SW_; ++j) {
        const uint want = ((j - 1) >> 2) & 1u;   // expected tag of step j-1 data
        const uint wtag = (j >> 2) & 1u;         // tag we write at step j

        // ---- P1: build all B-fragments (+ boundary polls) ----
        if (wv < 8) {
            u32x4 a = {0, 0, 0, 0}, b = {0, 0, 0, 0};
            if (j > 0 && !hskip) {
                const uint* p = hring + (size_t)((j - 1) & 3) * HSLOT + hn * 128 + hd0;
                poll2(p, p + 4, want, a, b);
            }
            float hv8[8];
            #pragma unroll
            for (int r = 0; r < 4; ++r) {
                hv8[r]     = __uint_as_float(a[r]);
                hv8[4 + r] = __uint_as_float(b[r]);
            }
            uint hw[4], lw[4];
            #pragma unroll
            for (int p = 0; p < 4; ++p) {
                uint2 e0 = splitbf(hv8[2 * p]), e1 = splitbf(hv8[2 * p + 1]);
                hw[p] = e0.x | (e1.x << 16);
                lw[p] = e0.y | (e1.y << 16);
            }
            *(uint4*)wp       = make_uint4(hw[0], hw[1], hw[2], hw[3]);
            *(uint4*)(wp + 4) = make_uint4(lw[0], lw[1], lw[2], lw[3]);
        } else {
            float xv[8];
            int w = j - xhr;
            if ((unsigned)w < (unsigned)W_) {
                if (use_xt) {
                    const float* xp = xt + (((size_t)xb * H_ + xhr) * W_ + w) * C_ + xc0;
                    f32x4 va = *(const f32x4*)xp, vb = *(const f32x4*)(xp + 4);
                    #pragma unroll
                    for (int r = 0; r < 4; ++r) { xv[r] = va[r]; xv[4 + r] = vb[r]; }
                } else {
                    #pragma unroll
                    for (int r = 0; r < 8; ++r)
                        xv[r] = x[(((size_t)xb * C_ + xc0 + r) * H_ + xhr) * W_ + w];
                }
            } else {
                #pragma unroll
                for (int r = 0; r < 8; ++r) xv[r] = 0.f;
            }
            uint hw[4], lw[4];
            #pragma unroll
            for (int p = 0; p < 4; ++p) {
                uint2 e0 = splitbf(xv[2 * p]), e1 = splitbf(xv[2 * p + 1]);
                hw[p] = e0.x | (e1.x << 16);
                lw[p] = e0.y | (e1.y << 16);
            }
            *(uint4*)wp       = make_uint4(hw[0], hw[1], hw[2], hw[3]);
            *(uint4*)(wp + 4) = make_uint4(lw[0], lw[1], lw[2], lw[3]);

            if (ii >= 0 && ii < 8) {                     // c-boundary poll (32 floats)
                if (inb && j > 0) {
                    u32x4 cv;
                    const uint* cp = cring +
                        (((size_t)((j - 1) & 3) * NCG + (cgp - 1)) * NG + g) * GH + ii * 4;
                    poll1(cp, want, cv);
                    #pragma unroll
                    for (int r = 0; r < 4; ++r)
                        Cs[j & 1][ii * 4 + r] = __uint_as_float(cv[r]);
                }
            } else if (ii == 8) {                        // WAR: right cluster read j-3
                if (j >= 4 && hasr) wait_ge(gcntp + (cgp + 1) * 32, 4 * (j - 2));
            }
        }
        __syncthreads();                                 // sync_a: Bf/Cs ready
        if (tid == 0) rbump(gcntp + cgp * 32);           // our step-(j-1) reads done

        // ---- GEMM: rows [wv*16,+16) x 16 cols, K=320, 4-term split-bf16 ----
        f32x4 acc = {0.f, 0.f, 0.f, 0.f};
        #pragma unroll
        for (int kt = 0; kt < NKT; ++kt) {
            const uint* bp = bfr + kt * 576;
            uint4 hb = *(const uint4*)bp;
            uint4 lb = *(const uint4*)(bp + 4);
            bf16x8 Bh = *(bf16x8*)&hb, Bl = *(bf16x8*)&lb;
            acc = __builtin_amdgcn_mfma_f32_16x16x32_bf16(Ahr[kt], Bh, acc, 0, 0, 0);
            acc = __builtin_amdgcn_mfma_f32_16x16x32_bf16(Ahr[kt], Bl, acc, 0, 0, 0);
            acc = __builtin_amdgcn_mfma_f32_16x16x32_bf16(Alr[kt], Bh, acc, 0, 0, 0);
            acc = __builtin_amdgcn_mfma_f32_16x16x32_bf16(Alr[kt], Bl, acc, 0, 0, 0);
        }
        #pragma unroll
        for (int r = 0; r < 4; ++r)
            Gp[(wv * 16 + quad * 4 + r) * GPS + colc] = acc[r];
        __syncthreads();                                 // sync_b: gates ready

        // ---- nonlin + state update + tagged ring stores (fire-and-forget) ----
        if (tid < GH * TC) {
            const int hl = tid & 31, col = tid >> 5;
            int n = n0 + col, b = n >> 6, hr = n & 63;
            float go  = Gp[(0 * GH + hl) * GPS + col] + bias_s[0 * GH + hl];
            float gfl = Gp[(1 * GH + hl) * GPS + col] + bias_s[1 * GH + hl];
            float gfu = Gp[(2 * GH + hl) * GPS + col] + bias_s[2 * GH + hl];
            float gi  = Gp[(3 * GH + hl) * GPS + col] + bias_s[3 * GH + hl];
            float gg  = Gp[(4 * GH + hl) * GPS + col] + bias_s[4 * GH + hl];
            float so = sigm(go), sfl = sigm(gfl), sfu = sigm(gfu), si = sigm(gi);
            float tg = tanh_fast(gg);
            float cp = Cs[j & 1][(col + 1) * GH + hl];
            float cs = Cs[j & 1][col * GH + hl];
            float cv = sfl * cp + sfu * cs + si * tg;
            float hv = so * tanh_fast(cv);
            Cs[(j + 1) & 1][(col + 1) * GH + hl] = cv;   // disjoint from boundary [0,32)

            uint pk = (__float_as_uint(hv) & ~1u) | wtag;   // tag in fp32 LSB: 2^-24
            stu_nw(hring + (size_t)(j & 3) * HSLOT + (size_t)n * 128 + g * GH + hl, pk);
            if (col == TC - 1) {
                uint cpk = (__float_as_uint(cv) & ~1u) | wtag;
                stu_nw(cring + (((size_t)(j & 3) * NCG + cgp) * NG + g) * GH + hl, cpk);
            }
            int w = j - hr;
            if ((unsigned)w < (unsigned)W_)
                out[(((size_t)b * HD_ + g * GH + hl) * H_ + hr) * W_ + w] = hv;
        }
        // no third barrier: Bf rewrite (next P1) is fenced by sync_b's GEMM
        // completion; Gp rewrite is fenced by next sync_a; Cs buffers alternate.
    }
}

// ---------------------------------------------------------------------------
extern "C" void kernel_launch(void* const* d_in, const int* in_sizes, int n_in,
                              void* d_out, int out_size, void* d_ws, size_t ws_size,
                              hipStream_t stream)
{
    const float* x    = (const float*)d_in[0];
    const float* w_is = (const float*)d_in[1];
    const float* b_is = (const float*)d_in[2];
    const float* w_ss = (const float*)d_in[3];
    const float* b_ss = (const float*)d_in[4];
    float* out = (float*)d_out;
    float* ws  = (float*)d_ws;

    const long long n_ws = (long long)(ws_size / 4);
    const int use_xt = (n_ws >= WS_XT) ? 1 : 0;

    hipLaunchKernelGGL(lstm_prep, dim3(1024), dim3(256), 0, stream,
                       w_is, w_ss, ws, n_ws);
    if (use_xt)
        hipLaunchKernelGGL(lstm_xpose, dim3(B_ * H_), dim3(256), 0, stream, x, ws);

    hipLaunchKernelGGL(lstm_persist, dim3(NG * NCG), dim3(NT), 0, stream,
                       x, ws, b_is, b_ss, out, ws, use_xt);
}

// Round 6
// 496.098 us; speedup vs baseline: 1.5099x; 1.1684x over previous
//
#include <hip/hip_runtime.h>

typedef __attribute__((ext_vector_type(8))) short bf16x8;
typedef __attribute__((ext_vector_type(4))) float f32x4;
typedef __attribute__((ext_vector_type(4))) uint  u32x4;
typedef __attribute__((ext_vector_type(2))) uint  u32x2;

// Problem constants
#define B_   16
#define C_   64
#define H_   64
#define W_   64
#define HD_  128
#define K_   320      // C + 2*HD
#define SW_  127      // H+W-1

// Decomposition: 4 hd-groups (32 hd each) x 64 col-clusters (16 cols each) = 256 blocks
#define NG    4
#define GH    32      // hd per group
#define NCG   64      // clusters
#define TC    16      // cols per cluster
#define NT    704     // threads per block (11 waves: 10 GEMM + 1 aux)
#define ROWS  160     // gate rows per block (5 gates x 32 hd)
#define NKT   10      // K/32 k-tiles
#define GPS   17      // gate-panel stride

// Workspace layout (float/uint offsets).
// h ring: 4 slots x 1024 cols x 128 hd, fp32 with pass-parity tag in the
// mantissa LSB (2^-24, numerically free). Per-word tags: data is its own
// flag, RAW chain = store -> poll-hit (1 MALL hop). Prep wipes rings to
// tag=1 (pass -1) so pass-0 polls can't accept residue.
#define HSLOT  131072LL
#define CBX    524288LL                    // c boundary ring: 4 x NCG x NG x GH
#define CNT    557056LL                    // (legacy region, zeroed)
#define GCNT   559104LL                    // 64 WAR tokens, stride 32 ints
#define AFB    561152LL                    // A-fragments: 204800 floats (hi+lo bf16)
#define AF_N   204800LL
#define XT     765952LL                    // xT[b][hr][w][c]
#define XT_N   4194304LL
#define WS_MIN (AFB + AF_N)
#define WS_XT  (XT + XT_N)

#define POLL_CAP (1 << 20)   // safety: a protocol bug fails absmax instead of hanging

__device__ __forceinline__ float sigm(float v) { return 1.f / (1.f + __expf(-v)); }
__device__ __forceinline__ float tanh_fast(float v) {
    float e = __expf(2.f * v);
    return 1.f - 2.f / (e + 1.f);
}

__device__ __forceinline__ int rload(int* p) {
    return __hip_atomic_load(p, __ATOMIC_RELAXED, __HIP_MEMORY_SCOPE_AGENT);
}
__device__ __forceinline__ void rbump(int* p) {
    __hip_atomic_fetch_add(p, 1, __ATOMIC_RELAXED, __HIP_MEMORY_SCOPE_AGENT);
}
__device__ __forceinline__ void wait_ge(int* p, int tgt) {
    int guard = 0;
    while (rload(p) < tgt) { if (++guard > POLL_CAP) break; }
    __atomic_signal_fence(__ATOMIC_ACQUIRE);
}

// Coherence-point (sc0 sc1) ops: bypass L1/L2; weights/xT stay L2-warm.
__device__ __forceinline__ void stu_nw(uint* p, uint v) {     // fire-and-forget
    asm volatile("global_store_dword %0, %1, off sc0 sc1" :: "v"(p), "v"(v) : "memory");
}
__device__ __forceinline__ void st2_nw(uint* p, u32x2 v) {    // paired store
    asm volatile("global_store_dwordx2 %0, %1, off sc0 sc1" :: "v"(p), "v"(v) : "memory");
}

// Poll one 16B chunk until every 32-bit word's LSB == want.
__device__ __forceinline__ void poll1(const uint* p, uint want, u32x4& A) {
    int guard = 0;
    while (true) {
        u32x4 a;
        asm volatile("global_load_dwordx4 %0, %1, off sc0 sc1\n\ts_waitcnt vmcnt(0)"
                     : "=&v"(a) : "v"(p) : "memory");
        uint m = a[0] & a[1] & a[2] & a[3];
        uint o = a[0] | a[1] | a[2] | a[3];
        bool ok = want ? ((m & 1u) != 0u) : ((o & 1u) == 0u);
        if (ok || ++guard > POLL_CAP) { A = a; return; }
    }
}

__device__ __forceinline__ uint bf16hi(uint u) { return (u + 0x7FFFu + ((u >> 16) & 1u)) >> 16; }
__device__ __forceinline__ uint2 splitbf(float v) {
    uint uh = bf16hi(__float_as_uint(v));
    float rl = v - __uint_as_float(uh << 16);
    uint ul = bf16hi(__float_as_uint(rl));
    return make_uint2(uh, ul);
}

// ---------------------------------------------------------------------------
// Prep: wipe rings to tag=1 (0x00000001); zero counters; build A-fragments
// (split-bf16, MFMA lane order).
// ---------------------------------------------------------------------------
__global__ void lstm_prep(const float* __restrict__ w_is,
                          const float* __restrict__ w_ss,
                          float* __restrict__ ws, long long n_ws)
{
    const long long stride = (long long)gridDim.x * blockDim.x;
    const long long t0 = (long long)blockIdx.x * blockDim.x + threadIdx.x;
    uint* wsu = (uint*)ws;

    for (long long i = t0; i < 524288LL + 32768LL; i += stride) {
        long long a = (i < 524288LL) ? i : (CBX + (i - 524288LL));
        stu_nw(wsu + a, 0x00000001u);
    }
    for (long long i = CNT + t0; i < CNT + 4096; i += stride)
        stu_nw(wsu + i, 0u);

    if (n_ws >= WS_MIN) {
        ushort* af = (ushort*)(ws + AFB);
        for (long long e = t0; e < AF_N; e += stride) {
            int idx   = (int)e;
            int chunk = idx >> 9;           // (g*NRT+rt)*NKT + kt
            int lane  = (idx >> 3) & 63;
            int jj    = idx & 7;
            int g  = chunk / (10 * NKT);
            int rm = chunk % (10 * NKT);
            int rt = rm / NKT, kt = rm % NKT;
            int m = lane & 15, quad = lane >> 4;
            int r = rt * 16 + m;
            int q = r >> 5, hl = r & 31;
            int o = q * HD_ + g * GH + hl;
            int k = kt * 32 + quad * 8 + jj;
            float v;
            if (k < C_)            v = w_is[o * C_ + k];
            else if (k < C_ + HD_) v = w_ss[(o * HD_ + (k - C_)) * 2 + 1];
            else                   v = w_ss[(o * HD_ + (k - C_ - HD_)) * 2 + 0];
            uint uh = bf16hi(__float_as_uint(v));
            float rl = v - __uint_as_float(uh << 16);
            uint ul = bf16hi(__float_as_uint(rl));
            int base = chunk * 1024 + lane * 16 + jj;   // ushort units
            af[base]     = (ushort)uh;
            af[base + 8] = (ushort)ul;
        }
    }
}

// ---------------------------------------------------------------------------
// Coalesced transpose: x[b][c][hr][w] -> xT[b][hr][w][c] via 64x64 LDS tile.
// ---------------------------------------------------------------------------
__global__ void lstm_xpose(const float* __restrict__ x, float* __restrict__ ws)
{
    __shared__ float L[64 * 65];
    const int b = blockIdx.x >> 6, hr = blockIdx.x & 63;
    const int tid = threadIdx.x;          // 256 threads
    #pragma unroll
    for (int it = 0; it < 16; ++it) {
        int c = it * 4 + (tid >> 6), w = tid & 63;
        L[c * 65 + w] = x[(((size_t)b * C_ + c) * H_ + hr) * W_ + w];
    }
    __syncthreads();
    float* xt = ws + XT;
    #pragma unroll
    for (int it = 0; it < 16; ++it) {
        int w = it * 4 + (tid >> 6), c = tid & 63;
        xt[(((size_t)b * H_ + hr) * W_ + w) * C_ + c] = L[c * 65 + w];
    }
}

// ---------------------------------------------------------------------------
// Persistent kernel: 127 diagonal steps, self-tagged dataflow with
// DEDUPLICATED polls: 544 threads each poll one distinct dwordx4 of the
// 17-col x 128-hd window (2176 words vs 4096 duplicated before) and write
// the 4 values into BOTH the unshifted (kt 2-5) and shifted (kt 6-9)
// B-fragments. 128 threads build x fragments (kt 0-1); c-poll/WAR on the
// 11th wave. 2 barriers/step; GEMM on waves 0-9 with 2 acc chains.
// ---------------------------------------------------------------------------
__global__ void __launch_bounds__(NT, 2) lstm_persist(
    const float* __restrict__ x,
    const float* __restrict__ ws_c,
    const float* __restrict__ b_is,
    const float* __restrict__ b_ss,
    float* __restrict__ out,
    float* __restrict__ ws,
    int use_xt)
{
    __shared__ uint  Bf[NKT * 576];     // B-fragments: per kt, 64 lanes x (16B hi + 16B lo)
    __shared__ float Gp[ROWS * GPS];    // gate panel
    __shared__ float Cs[2][17 * GH];    // double-buffered c panel [colp][hl]
    __shared__ float bias_s[ROWS];

    const int tid = threadIdx.x;
    const int cgp = blockIdx.x >> 2;
    const int g   = blockIdx.x & 3;
    const int n0  = cgp * TC;
    const int inb  = (n0 & 63) != 0;
    const int hasr = ((n0 + TC) & 63) != 0;

    uint* hring = (uint*)ws;
    uint* cring = (uint*)(ws + CBX);
    int*  gcntp = (int*)(ws + GCNT);
    const float* xt = ws_c + XT;
    const uint4* afq = (const uint4*)(ws_c + AFB);

    if (tid < ROWS) {
        int q = tid >> 5, hl = tid & 31;
        int o = q * HD_ + g * GH + hl;
        bias_s[tid] = b_is[o] + b_ss[o];
    }
    if (tid < 17 * GH) Cs[0][tid] = 0.f;    // step-0 c panel
    if (tid >= 544 && tid < 544 + GH) Cs[1][tid - 544] = 0.f;   // boundary col, buf 1

    const int lane = tid & 63;
    const int wv   = tid >> 6;          // waves 0-9 = GEMM row-tiles
    const int quad = lane >> 4;
    const int colc = lane & 15;
    uint* bfr = &Bf[lane * 8 + ((lane >> 2) << 2)];   // GEMM read base

    // ---- poll-thread constants (tid < 544): one dwordx4 of the h window ----
    const int cp  = tid >> 5;           // window col 0..16 (global col n0-1+cp)
    const int ch  = tid & 31;           // hd chunk: hd = ch*4
    const int pq  = (ch >> 1) & 3;      // quad of the fragment lane
    const int pj0 = (ch & 1) * 4;       // jj offset (0 or 4)
    const int kta = 2 + (ch >> 3);      // unshifted k-tile (cols n0..n0+15)
    const int laneA = pq * 16 + ((cp >= 1) ? (cp - 1) : 0);
    const int laneB = pq * 16 + ((cp <= 15) ? cp : 0);
    uint* bfA = &Bf[laneA * 8 + ((laneA >> 2) << 2) + kta * 576 + (pj0 >> 1)];
    uint* bfB = &Bf[laneB * 8 + ((laneB >> 2) << 2) + (kta + 4) * 576 + (pj0 >> 1)];
    const uint* hbase = hring + (size_t)(n0 - 1 + cp) * 128 + ch * 4;
    const int pskip = (cp == 0 && !inb);

    // ---- x-thread constants (544 <= tid < 672): one lane of kt 0/1 ----
    const int xi = tid - 544;
    const int xkt = xi >> 6, xl = xi & 63;
    const int xq = xl >> 4, xcolc = xl & 15;
    const int xc0 = xkt * 32 + xq * 8;
    const int xn = n0 + xcolc, xb = xn >> 6, xhr = xn & 63;
    uint* bfX = &Bf[xl * 8 + ((xl >> 2) << 2) + xkt * 576];

    const int ci = tid - 672;           // 0..7: c-boundary poll; ==8: WAR wait

    // ---- A hi AND lo fragments pinned in registers (GEMM waves only) ----
    bf16x8 Ahr[NKT], Alr[NKT];
    if (wv < 10) {
        const uint4* ap0 = afq + (size_t)((g * 10 + wv) * NKT) * 128 + lane * 2;
        #pragma unroll
        for (int kt = 0; kt < NKT; ++kt) {
            uint4 ha = ap0[kt * 128];
            Ahr[kt] = *(bf16x8*)&ha;
            asm volatile("" : "+v"(Ahr[kt]));
            uint4 la = ap0[kt * 128 + 1];
            Alr[kt] = *(bf16x8*)&la;
            asm volatile("" : "+v"(Alr[kt]));
        }
    }

    __syncthreads();

    for (int j = 0; j < SW_; ++j) {
        const uint want = ((j - 1) >> 2) & 1u;   // expected tag of step j-1 data
        const uint wtag = (j >> 2) & 1u;         // tag we write at step j

        // ---- P1: build all B-fragments (dedup polls) + boundary work ----
        if (tid < 544) {
            u32x4 a = {0, 0, 0, 0};
            if (j > 0 && !pskip)
                poll1(hbase + (size_t)((j - 1) & 3) * HSLOT, want, a);
            uint2 e0 = splitbf(__uint_as_float(a[0]));
            uint2 e1 = splitbf(__uint_as_float(a[1]));
            uint2 e2 = splitbf(__uint_as_float(a[2]));
            uint2 e3 = splitbf(__uint_as_float(a[3]));
            u32x2 hp = {e0.x | (e1.x << 16), e2.x | (e3.x << 16)};
            u32x2 lp = {e0.y | (e1.y << 16), e2.y | (e3.y << 16)};
            if (cp >= 1)  { *(u32x2*)bfA = hp; *(u32x2*)(bfA + 4) = lp; }
            if (cp <= 15) { *(u32x2*)bfB = hp; *(u32x2*)(bfB + 4) = lp; }
        } else if (tid < 672) {
            float xv[8];
            int w = j - xhr;
            if ((unsigned)w < (unsigned)W_) {
                if (use_xt) {
                    const float* xp = xt + (((size_t)xb * H_ + xhr) * W_ + w) * C_ + xc0;
                    f32x4 va = *(const f32x4*)xp, vb = *(const f32x4*)(xp + 4);
                    #pragma unroll
                    for (int r = 0; r < 4; ++r) { xv[r] = va[r]; xv[4 + r] = vb[r]; }
                } else {
                    #pragma unroll
                    for (int r = 0; r < 8; ++r)
                        xv[r] = x[(((size_t)xb * C_ + xc0 + r) * H_ + xhr) * W_ + w];
                }
            } else {
                #pragma unroll
                for (int r = 0; r < 8; ++r) xv[r] = 0.f;
            }
            uint hw[4], lw[4];
            #pragma unroll
            for (int p = 0; p < 4; ++p) {
                uint2 e0 = splitbf(xv[2 * p]), e1 = splitbf(xv[2 * p + 1]);
                hw[p] = e0.x | (e1.x << 16);
                lw[p] = e0.y | (e1.y << 16);
            }
            *(uint4*)bfX       = make_uint4(hw[0], hw[1], hw[2], hw[3]);
            *(uint4*)(bfX + 4) = make_uint4(lw[0], lw[1], lw[2], lw[3]);
        } else if (ci >= 0 && ci < 8) {              // c-boundary poll (32 floats)
            if (inb && j > 0) {
                u32x4 cv;
                const uint* cpx = cring +
                    (((size_t)((j - 1) & 3) * NCG + (cgp - 1)) * NG + g) * GH + ci * 4;
                poll1(cpx, want, cv);
                #pragma unroll
                for (int r = 0; r < 4; ++r)
                    Cs[j & 1][ci * 4 + r] = __uint_as_float(cv[r]);
            }
        } else if (ci == 8) {                        // WAR: right cluster read j-3
            if (j >= 4 && hasr) wait_ge(gcntp + (cgp + 1) * 32, 4 * (j - 2));
        }
        __syncthreads();                             // sync_a: Bf/Cs ready
        if (tid == 0) rbump(gcntp + cgp * 32);       // our step-(j-1) reads done

        // ---- GEMM: rows [wv*16,+16) x 16 cols, K=320, 2 acc chains ----
        if (wv < 10) {
            f32x4 acc0 = {0.f, 0.f, 0.f, 0.f};
            f32x4 acc1 = {0.f, 0.f, 0.f, 0.f};
            __builtin_amdgcn_s_setprio(1);
            #pragma unroll
            for (int kt = 0; kt < NKT; kt += 2) {
                const uint* bp0 = bfr + kt * 576;
                uint4 hb0 = *(const uint4*)bp0;
                uint4 lb0 = *(const uint4*)(bp0 + 4);
                const uint* bp1 = bfr + (kt + 1) * 576;
                uint4 hb1 = *(const uint4*)bp1;
                uint4 lb1 = *(const uint4*)(bp1 + 4);
                bf16x8 Bh0 = *(bf16x8*)&hb0, Bl0 = *(bf16x8*)&lb0;
                bf16x8 Bh1 = *(bf16x8*)&hb1, Bl1 = *(bf16x8*)&lb1;
                acc0 = __builtin_amdgcn_mfma_f32_16x16x32_bf16(Ahr[kt],     Bh0, acc0, 0, 0, 0);
                acc1 = __builtin_amdgcn_mfma_f32_16x16x32_bf16(Ahr[kt + 1], Bh1, acc1, 0, 0, 0);
                acc0 = __builtin_amdgcn_mfma_f32_16x16x32_bf16(Ahr[kt],     Bl0, acc0, 0, 0, 0);
                acc1 = __builtin_amdgcn_mfma_f32_16x16x32_bf16(Ahr[kt + 1], Bl1, acc1, 0, 0, 0);
                acc0 = __builtin_amdgcn_mfma_f32_16x16x32_bf16(Alr[kt],     Bh0, acc0, 0, 0, 0);
                acc1 = __builtin_amdgcn_mfma_f32_16x16x32_bf16(Alr[kt + 1], Bh1, acc1, 0, 0, 0);
                acc0 = __builtin_amdgcn_mfma_f32_16x16x32_bf16(Alr[kt],     Bl0, acc0, 0, 0, 0);
                acc1 = __builtin_amdgcn_mfma_f32_16x16x32_bf16(Alr[kt + 1], Bl1, acc1, 0, 0, 0);
            }
            __builtin_amdgcn_s_setprio(0);
            #pragma unroll
            for (int r = 0; r < 4; ++r)
                Gp[(wv * 16 + quad * 4 + r) * GPS + colc] = acc0[r] + acc1[r];
        }
        __syncthreads();                             // sync_b: gates ready

        // ---- nonlin + state update + tagged ring stores (fire-and-forget) ----
        if (tid < GH * TC) {
            const int hl = tid & 31, col = tid >> 5;
            int n = n0 + col, b = n >> 6, hr = n & 63;
            float go  = Gp[(0 * GH + hl) * GPS + col] + bias_s[0 * GH + hl];
            float gfl = Gp[(1 * GH + hl) * GPS + col] + bias_s[1 * GH + hl];
            float gfu = Gp[(2 * GH + hl) * GPS + col] + bias_s[2 * GH + hl];
            float gi  = Gp[(3 * GH + hl) * GPS + col] + bias_s[3 * GH + hl];
            float gg  = Gp[(4 * GH + hl) * GPS + col] + bias_s[4 * GH + hl];
            float so = sigm(go), sfl = sigm(gfl), sfu = sigm(gfu), si = sigm(gi);
            float tg = tanh_fast(gg);
            float cp_ = Cs[j & 1][(col + 1) * GH + hl];
            float cs = Cs[j & 1][col * GH + hl];
            float cv = sfl * cp_ + sfu * cs + si * tg;
            float hv = so * tanh_fast(cv);
            Cs[(j + 1) & 1][(col + 1) * GH + hl] = cv;   // disjoint from boundary [0,32)

            uint pk = (__float_as_uint(hv) & ~1u) | wtag;   // tag in fp32 LSB: 2^-24
            uint other = (uint)__shfl_xor((int)pk, 1);
            if (!(hl & 1)) {                                // paired store: 2 hd per req
                u32x2 pv = {pk, other};
                st2_nw(hring + (size_t)(j & 3) * HSLOT + (size_t)n * 128 + g * GH + (hl & ~1), pv);
            }
            if (col == TC - 1) {
                uint cpk = (__float_as_uint(cv) & ~1u) | wtag;
                stu_nw(cring + (((size_t)(j & 3) * NCG + cgp) * NG + g) * GH + hl, cpk);
            }
            int w = j - hr;
            if ((unsigned)w < (unsigned)W_)
                out[(((size_t)b * HD_ + g * GH + hl) * H_ + hr) * W_ + w] = hv;
        }
        // no third barrier: Bf rewrite (next P1) is fenced by sync_b (GEMM reads
        // done); Gp rewrite fenced by next sync_a; Cs buffers alternate.
    }
}

// ---------------------------------------------------------------------------
extern "C" void kernel_launch(void* const* d_in, const int* in_sizes, int n_in,
                              void* d_out, int out_size, void* d_ws, size_t ws_size,
                              hipStream_t stream)
{
    const float* x    = (const float*)d_in[0];
    const float* w_is = (const float*)d_in[1];
    const float* b_is = (const float*)d_in[2];
    const float* w_ss = (const float*)d_in[3];
    const float* b_ss = (const float*)d_in[4];
    float* out = (float*)d_out;
    float* ws  = (float*)d_ws;

    const long long n_ws = (long long)(ws_size / 4);
    const int use_xt = (n_ws >= WS_XT) ? 1 : 0;

    hipLaunchKernelGGL(lstm_prep, dim3(1024), dim3(256), 0, stream,
                       w_is, w_ss, ws, n_ws);
    if (use_xt)
        hipLaunchKernelGGL(lstm_xpose, dim3(B_ * H_), dim3(256), 0, stream, x, ws);

    hipLaunchKernelGGL(lstm_persist, dim3(NG * NCG), dim3(NT), 0, stream,
                       x, ws, b_is, b_ss, out, ws, use_xt);
}